// Round 6
// baseline (508.855 us; speedup 1.0000x reference)
//
#include <hip/hip_runtime.h>

#define HID   2048
#define S_LEN 2048
#define NHEAD 16
#define HD    128
#define NKV   2048   // NH*HD

typedef __attribute__((ext_vector_type(8))) short   short8;
typedef __attribute__((ext_vector_type(4))) float   floatx4;

__device__ __forceinline__ unsigned short f2bf(float f) {
    union { float f; unsigned u; } v; v.f = f;
    unsigned r = v.u + 0x7fffu + ((v.u >> 16) & 1u);
    return (unsigned short)(r >> 16);
}
__device__ __forceinline__ float bf2f(unsigned short h) {
    union { unsigned u; float f; } v; v.u = ((unsigned)h) << 16; return v.f;
}

// async global->LDS, 16B per lane; LDS dest must be wave-uniform base + lane*16
__device__ __forceinline__ void async16(void* lds, const void* g) {
    __builtin_amdgcn_global_load_lds(
        (const __attribute__((address_space(1))) unsigned int*)g,
        (__attribute__((address_space(3))) unsigned int*)lds, 16, 0, 0);
}

// ---------------- RMSNorm: x(f32) -> h(bf16) ----------------
__global__ __launch_bounds__(256) void rmsnorm_kernel(const float* __restrict__ x,
        const float* __restrict__ w, unsigned short* __restrict__ h) {
    const int row = blockIdx.x;
    const int t = threadIdx.x;
    const float* xr = x + (size_t)row * HID;
    float4 v0 = *(const float4*)(xr + t * 4);
    float4 v1 = *(const float4*)(xr + 1024 + t * 4);
    float ss = v0.x*v0.x + v0.y*v0.y + v0.z*v0.z + v0.w*v0.w
             + v1.x*v1.x + v1.y*v1.y + v1.z*v1.z + v1.w*v1.w;
    #pragma unroll
    for (int off = 1; off < 64; off <<= 1) ss += __shfl_xor(ss, off, 64);
    __shared__ float red[4];
    if ((t & 63) == 0) red[t >> 6] = ss;
    __syncthreads();
    float tot = red[0] + red[1] + red[2] + red[3];
    float inv = rsqrtf(tot * (1.0f / HID) + 1e-5f);
    float4 w0 = *(const float4*)(w + t * 4);
    float4 w1 = *(const float4*)(w + 1024 + t * 4);
    ushort4 o0, o1;
    o0.x = f2bf(v0.x * inv * w0.x); o0.y = f2bf(v0.y * inv * w0.y);
    o0.z = f2bf(v0.z * inv * w0.z); o0.w = f2bf(v0.w * inv * w0.w);
    o1.x = f2bf(v1.x * inv * w1.x); o1.y = f2bf(v1.y * inv * w1.y);
    o1.z = f2bf(v1.z * inv * w1.z); o1.w = f2bf(v1.w * inv * w1.w);
    *(ushort4*)(h + (size_t)row * HID + t * 4) = o0;
    *(ushort4*)(h + (size_t)row * HID + 1024 + t * 4) = o1;
}

// ------------- weight cast+transpose: W[k][n](f32) -> Wt[n][k](bf16) -------------
__global__ __launch_bounds__(256) void wtrans_kernel(const float* __restrict__ Wq,
        const float* __restrict__ Wk, const float* __restrict__ Wv,
        const float* __restrict__ Wo,
        unsigned short* __restrict__ wt_qkv, unsigned short* __restrict__ wt_o) {
    __shared__ float tile[64][65];
    const int sel = blockIdx.z;
    const float* W = (sel == 0) ? Wq : (sel == 1) ? Wk : (sel == 2) ? Wv : Wo;
    const int n0 = blockIdx.x * 64, k0 = blockIdx.y * 64;
    const int t = threadIdx.x;
    const int col = t & 63, r4 = t >> 6;
    #pragma unroll
    for (int i = 0; i < 16; ++i) {
        int rr = r4 + i * 4;
        tile[rr][col] = W[(size_t)(k0 + rr) * NKV + n0 + col];
    }
    __syncthreads();
    #pragma unroll
    for (int i = 0; i < 16; ++i) {
        int rr = r4 + i * 4;
        unsigned short v = f2bf(tile[col][rr]);
        if (sel < 3) wt_qkv[((size_t)(sel * 2048 + n0 + rr)) * HID + k0 + col] = v;
        else         wt_o  [((size_t)(n0 + rr)) * HID + k0 + col] = v;
    }
}

// ------------- GEMM mainloop: C(128x128) = A[M][K](bf16) * Bt[N][K](bf16)^T -------------
// LDS tiles XOR-swizzled (16B chunk c at row r stored at slot c^(r&7)).
// Wave column mapping: cols(ni) = ni*32 + (w&1)*16 + lr  (pairs d,d+64 in same wave).
__device__ __forceinline__ void gemm_body(const unsigned short* __restrict__ A,
        const unsigned short* __restrict__ Bt, int K, int rowBase, int colBase,
        unsigned short* As, unsigned short* Bs, floatx4 acc[4][4]) {
    const int t = threadIdx.x;
    const int lane = t & 63, w = t >> 6;
    const int wm = (w >> 1) * 64, wsel = w & 1;
    const int lr = lane & 15, quad = lane >> 4;
    #pragma unroll
    for (int mi = 0; mi < 4; ++mi)
        #pragma unroll
        for (int ni = 0; ni < 4; ++ni) {
            acc[mi][ni][0] = 0.f; acc[mi][ni][1] = 0.f;
            acc[mi][ni][2] = 0.f; acc[mi][ni][3] = 0.f;
        }
    for (int k0 = 0; k0 < K; k0 += 64) {
        __syncthreads();
        #pragma unroll
        for (int c = 0; c < 4; ++c) {
            int e = (c * 256 + t) * 8;          // LDS element offset
            int r = e >> 6;                     // tile row
            int chunk = ((e >> 3) & 7) ^ (r & 7);  // logical 8-el chunk
            async16(As + e, A  + (size_t)(rowBase + r) * K + k0 + chunk * 8);
            async16(Bs + e, Bt + (size_t)(colBase + r) * K + k0 + chunk * 8);
        }
        __syncthreads();
        #pragma unroll
        for (int ks = 0; ks < 2; ++ks) {
            short8 af[4], bfr[4];
            int cp = (ks * 4 + quad) ^ (lr & 7);
            #pragma unroll
            for (int i = 0; i < 4; ++i)
                af[i] = *(const short8*)(As + (wm + i * 16 + lr) * 64 + cp * 8);
            #pragma unroll
            for (int i = 0; i < 4; ++i)
                bfr[i] = *(const short8*)(Bs + (i * 32 + wsel * 16 + lr) * 64 + cp * 8);
            #pragma unroll
            for (int mi = 0; mi < 4; ++mi)
                #pragma unroll
                for (int ni = 0; ni < 4; ++ni)
                    acc[mi][ni] = __builtin_amdgcn_mfma_f32_16x16x32_bf16(
                        af[mi], bfr[ni], acc[mi][ni], 0, 0, 0);
        }
    }
}

// ------------- QKV GEMM: h @ Wqkv, fused RoPE; scatters q,k (b,h,s,d) and v^T (b,h,d,s) -------------
__global__ __launch_bounds__(256) void gemm_qkv_kernel(const unsigned short* __restrict__ h,
        const unsigned short* __restrict__ wt, const float* __restrict__ cosp,
        const float* __restrict__ sinp, unsigned short* __restrict__ qk,
        unsigned short* __restrict__ vT) {
    __shared__ __align__(16) unsigned short As[128 * 64];
    __shared__ __align__(16) unsigned short Bs[128 * 64];
    floatx4 acc[4][4];
    const int rowBase = blockIdx.y * 128, colBase = blockIdx.x * 128;
    gemm_body(h, wt, HID, rowBase, colBase, As, Bs, acc);
    const int t = threadIdx.x, lane = t & 63, w = t >> 6;
    const int wm = (w >> 1) * 64, wsel = w & 1;
    const int lr = lane & 15, quad = lane >> 4;
    const int sel = colBase >> 11;
    const int hh = (colBase >> 7) & 15;
    #pragma unroll
    for (int mi = 0; mi < 4; ++mi) {
        int row0 = rowBase + wm + mi * 16 + quad * 4;
        int b = row0 >> 11, s0 = row0 & 2047;
        if (sel < 2) {
            unsigned short* base = qk + (size_t)sel * 8388608
                                 + ((size_t)(b * NHEAD + hh) * S_LEN) * HD;
            #pragma unroll
            for (int ni = 0; ni < 2; ++ni) {
                int d = ni * 32 + wsel * 16 + lr;      // [0,64)
                #pragma unroll
                for (int r = 0; r < 4; ++r) {
                    int s = s0 + r;
                    float c  = cosp[s * 64 + d];
                    float sn = sinp[s * 64 + d];
                    float v1 = acc[mi][ni][r], v2 = acc[mi][ni + 2][r];
                    base[(size_t)s * HD + d]      = f2bf(v1 * c - v2 * sn);
                    base[(size_t)s * HD + d + 64] = f2bf(v2 * c + v1 * sn);
                }
            }
        } else {
            #pragma unroll
            for (int ni = 0; ni < 4; ++ni) {
                int d = ni * 32 + wsel * 16 + lr;
                ushort4 pk;
                pk.x = f2bf(acc[mi][ni][0]); pk.y = f2bf(acc[mi][ni][1]);
                pk.z = f2bf(acc[mi][ni][2]); pk.w = f2bf(acc[mi][ni][3]);
                *(ushort4*)(vT + ((size_t)(b * NHEAD + hh) * HD + d) * S_LEN + s0) = pk;
            }
        }
    }
}

// ------------- causal flash attention, barrier-free register streaming -------------
// Uniform-work blocks (17 k-tiles each, 2-way key split per q-tile pair). K and V
// fragments stream straight from global memory into VGPRs (L1/L2/L3 absorb the 4x
// intra-block redundancy); LDS holds only the wave-private P round-trip. No
// __syncthreads in the k-loop. Fixed softmax max=0, partials combined later.
__global__ __launch_bounds__(256, 2) void attn_kernel(const unsigned short* __restrict__ q,
        const unsigned short* __restrict__ k, const unsigned short* __restrict__ vT,
        unsigned short* __restrict__ Opart, float* __restrict__ lpart) {
    __shared__ __align__(16) unsigned short Ps[4][32 * 64];   // per-wave P, 8-chunk xor swizzle

    const int id = blockIdx.x;            // 0..511
    const int bh   = id >> 4;             // 0..31
    const int j    = (id >> 1) & 7;       // 0..7
    const int role = id & 1;              // 0=A (first halves), 1=B (second halves)

    const int qtA = 15 - j, qtB = j;
    const int n1 = 16 - j;                // seg1 iters (q-tile qtA)
    const int n2 = j + 1;                 // seg2 iters (q-tile qtB)
    const int segqt[2] = {qtA, qtB};
    const int segk0[2] = {role ? n1 : 0, role ? n2 : 0};
    const int seglen[2] = {n1, n2};

    const unsigned short* qb = q  + (size_t)bh * S_LEN * HD;
    const unsigned short* kb = k  + (size_t)bh * S_LEN * HD;
    const unsigned short* vb = vT + (size_t)bh * HD * S_LEN;
    const int t = threadIdx.x, lane = t & 63, w = t >> 6;
    const int lr = lane & 15, quad = lane >> 4;
    const float SC = 0.1275174855f;  // (1/sqrt(128)) * log2(e)

    short8 qf[2][4];      // Q frags, pre-scaled
    short8 kf[4][4];      // current K tile [ks][ni]
    short8 vf[8];         // V half-tile [nt]
    floatx4 o[2][8];
    float rs[2][4];
    #pragma unroll
    for (int mi = 0; mi < 2; ++mi) {
        #pragma unroll
        for (int i = 0; i < 8; ++i) { o[mi][i][0]=0.f; o[mi][i][1]=0.f; o[mi][i][2]=0.f; o[mi][i][3]=0.f; }
        rs[mi][0]=0.f; rs[mi][1]=0.f; rs[mi][2]=0.f; rs[mi][3]=0.f;
    }

    auto loadq = [&](int qt) {
        #pragma unroll
        for (int mi = 0; mi < 2; ++mi) {
            int qrow = qt * 128 + mi * 64 + w * 16 + lr;
            #pragma unroll
            for (int ks = 0; ks < 4; ++ks) {
                short8 raw = *(const short8*)(qb + (size_t)qrow * HD + ks * 32 + quad * 8);
                #pragma unroll
                for (int jj = 0; jj < 8; ++jj)
                    qf[mi][ks][jj] = (short)f2bf(bf2f((unsigned short)raw[jj]) * SC);
            }
        }
    };

    auto loadK = [&](int kt2) {
        #pragma unroll
        for (int ks = 0; ks < 4; ++ks)
            #pragma unroll
            for (int ni = 0; ni < 4; ++ni)
                kf[ks][ni] = *(const short8*)(kb
                    + (size_t)(kt2 * 64 + ni * 16 + lr) * HD + ks * 32 + quad * 8);
    };

    auto loadV = [&](int kt2, int half) {
        #pragma unroll
        for (int nt = 0; nt < 8; ++nt)
            vf[nt] = *(const short8*)(vb
                + (size_t)(nt * 16 + lr) * S_LEN + kt2 * 64 + half * 32 + quad * 8);
    };

    // flush partials for q-tile qt, reset accumulators
    auto flushseg = [&](int qt) {
        unsigned short* ob = Opart + (size_t)role * 8388608
                           + ((size_t)(bh * 16 + qt) * 128) * 128;
        float* lb = lpart + role * 65536 + (bh * 16 + qt) * 128;
        #pragma unroll
        for (int mi = 0; mi < 2; ++mi) {
            int qrow0 = mi * 64 + w * 16 + quad * 4;
            #pragma unroll
            for (int r = 0; r < 4; ++r) {
                float s2 = rs[mi][r];
                #pragma unroll
                for (int off = 1; off < 16; off <<= 1) s2 += __shfl_xor(s2, off, 64);
                if (lr == 0) lb[qrow0 + r] = s2;
            }
            #pragma unroll
            for (int nt = 0; nt < 8; ++nt) {
                int col = nt * 16 + lr;
                #pragma unroll
                for (int r = 0; r < 4; ++r)
                    ob[(size_t)(qrow0 + r) * 128 + col] = f2bf(o[mi][nt][r]);
            }
            #pragma unroll
            for (int i = 0; i < 8; ++i) { o[mi][i][0]=0.f; o[mi][i][1]=0.f; o[mi][i][2]=0.f; o[mi][i][3]=0.f; }
            rs[mi][0]=0.f; rs[mi][1]=0.f; rs[mi][2]=0.f; rs[mi][3]=0.f;
        }
    };

    loadK(segk0[0]);
    for (int s = 0; s < 2; ++s) {
        loadq(segqt[s]);
        const int qt = segqt[s], k0 = segk0[s], len = seglen[s];
        for (int i = 0; i < len; ++i) {
            const int kt = k0 + i;
            // V half0 loads — consumed after softmax (latency covered by QK+softmax)
            loadV(kt, 0);
            // ---- QK^T (consumes kf) ----
            floatx4 sc[2][4];
            #pragma unroll
            for (int mi = 0; mi < 2; ++mi)
                #pragma unroll
                for (int ni = 0; ni < 4; ++ni) { sc[mi][ni][0]=0.f; sc[mi][ni][1]=0.f; sc[mi][ni][2]=0.f; sc[mi][ni][3]=0.f; }
            #pragma unroll
            for (int ks = 0; ks < 4; ++ks)
                #pragma unroll
                for (int ni = 0; ni < 4; ++ni) {
                    sc[0][ni] = __builtin_amdgcn_mfma_f32_16x16x32_bf16(qf[0][ks], kf[ks][ni], sc[0][ni], 0, 0, 0);
                    sc[1][ni] = __builtin_amdgcn_mfma_f32_16x16x32_bf16(qf[1][ks], kf[ks][ni], sc[1][ni], 0, 0, 0);
                }
            // prefetch next K tile (WAR on kf is safe once QK has issued)
            {
                int ns = s, nidx = i + 1;
                if (nidx == len) { ns = s + 1; nidx = 0; }
                int nk = (ns < 2) ? (segk0[ns & 1] + nidx) : kt;  // harmless reload at very end
                loadK(nk);
            }
            // ---- softmax numerator (fixed max=0), P to wave-private LDS ----
            const bool maskf = (kt >= 2 * qt);
            #pragma unroll
            for (int mi = 0; mi < 2; ++mi) {
                int row_out = qt * 128 + mi * 64 + w * 16 + quad * 4;
                #pragma unroll
                for (int ni = 0; ni < 4; ++ni) {
                    int key = kt * 64 + ni * 16 + lr;
                    #pragma unroll
                    for (int r = 0; r < 4; ++r) {
                        float p = exp2f(sc[mi][ni][r]);
                        if (maskf && key > row_out + r) p = 0.f;
                        rs[mi][r] += p;
                        int prow = mi * 16 + quad * 4 + r;
                        int chunk = (ni * 2 + (lr >> 3)) ^ (prow & 7);
                        Ps[w][prow * 64 + chunk * 8 + (lr & 7)] =
                            (unsigned short)(__float_as_uint(p) >> 16);
                    }
                }
            }
            // ---- P @ V ----
            #pragma unroll
            for (int ks2 = 0; ks2 < 2; ++ks2) {
                int pcp = (ks2 * 4 + quad) ^ (lr & 7);
                short8 pa0 = *(const short8*)(&Ps[w][(lr) * 64 + pcp * 8]);
                short8 pa1 = *(const short8*)(&Ps[w][(16 + lr) * 64 + pcp * 8]);
                #pragma unroll
                for (int nt = 0; nt < 8; ++nt) {
                    o[0][nt] = __builtin_amdgcn_mfma_f32_16x16x32_bf16(pa0, vf[nt], o[0][nt], 0, 0, 0);
                    o[1][nt] = __builtin_amdgcn_mfma_f32_16x16x32_bf16(pa1, vf[nt], o[1][nt], 0, 0, 0);
                }
                if (ks2 == 0) loadV(kt, 1);   // reload vf with half1 after PV0 issued
            }
        }
        flushseg(qt);
    }
}

// ------------- combine partials: attn = (OA+OB) / (lA+lB) -------------
__global__ __launch_bounds__(256) void combine_kernel(const unsigned short* __restrict__ Opart,
        const float* __restrict__ lpart, unsigned short* __restrict__ attn) {
    const int T = blockIdx.x;        // bh*16 + qt
    const int bh = T >> 4, qt = T & 15;
    const int b = bh >> 4, hh = bh & 15;
    const int t = threadIdx.x;
    const int qrow = t >> 1, half = t & 1;
    float rl = 1.0f / (lpart[T * 128 + qrow] + lpart[65536 + T * 128 + qrow]);
    const unsigned short* pa = Opart + ((size_t)T * 128 + qrow) * 128 + half * 64;
    const unsigned short* pb = Opart + 8388608 + ((size_t)T * 128 + qrow) * 128 + half * 64;
    unsigned short* po = attn + ((size_t)(b * S_LEN + qt * 128 + qrow)) * NKV + hh * HD + half * 64;
    #pragma unroll
    for (int c = 0; c < 8; ++c) {
        short8 a8 = *(const short8*)(pa + c * 8);
        short8 b8 = *(const short8*)(pb + c * 8);
        short8 o8;
        #pragma unroll
        for (int jj = 0; jj < 8; ++jj)
            o8[jj] = (short)f2bf((bf2f((unsigned short)a8[jj]) + bf2f((unsigned short)b8[jj])) * rl);
        *(short8*)(po + c * 8) = o8;
    }
}

// ------------- output GEMM + residual -------------
__global__ __launch_bounds__(256) void gemm_out_kernel(const unsigned short* __restrict__ attn,
        const unsigned short* __restrict__ wto, const float* __restrict__ x,
        float* __restrict__ out) {
    __shared__ __align__(16) unsigned short As[128 * 64];
    __shared__ __align__(16) unsigned short Bs[128 * 64];
    floatx4 acc[4][4];
    const int rowBase = blockIdx.y * 128, colBase = blockIdx.x * 128;
    gemm_body(attn, wto, NKV, rowBase, colBase, As, Bs, acc);
    const int t = threadIdx.x, lane = t & 63, w = t >> 6;
    const int wm = (w >> 1) * 64, wsel = w & 1;
    const int lr = lane & 15, quad = lane >> 4;
    #pragma unroll
    for (int mi = 0; mi < 4; ++mi) {
        int row0 = rowBase + wm + mi * 16 + quad * 4;
        #pragma unroll
        for (int ni = 0; ni < 4; ++ni) {
            int col = colBase + ni * 32 + wsel * 16 + lr;
            #pragma unroll
            for (int r = 0; r < 4; ++r) {
                size_t off = (size_t)(row0 + r) * HID + col;
                out[off] = acc[mi][ni][r] + x[off];
            }
        }
    }
}

extern "C" void kernel_launch(void* const* d_in, const int* in_sizes, int n_in,
                              void* d_out, int out_size, void* d_ws, size_t ws_size,
                              hipStream_t stream) {
    const float* x     = (const float*)d_in[0];
    const float* rms_w = (const float*)d_in[1];
    const float* Wq    = (const float*)d_in[2];
    const float* Wk    = (const float*)d_in[3];
    const float* Wv    = (const float*)d_in[4];
    const float* Wo    = (const float*)d_in[5];
    const float* cosp  = (const float*)d_in[6];
    const float* sinp  = (const float*)d_in[7];
    float* out = (float*)d_out;

    unsigned short* ws   = (unsigned short*)d_ws;
    unsigned short* h    = ws;                   //  8388608 el (dead after qkv -> Opart role A)
    unsigned short* wtq  = ws + 8388608;         // 12582912 el (dead after qkv -> Opart role B + lpart)
    unsigned short* wto  = ws + 20971520;        //  4194304 el (Wo^T)
    unsigned short* qk   = ws + 25165824;        //  q then k, 2x8388608
    unsigned short* vT   = ws + 41943040;        //  8388608 el (b,h,d,s)
    unsigned short* attn = ws + 50331648;        //  8388608 el (b*s, h*d)
    unsigned short* Opart = ws;                  //  2 x 8388608 el (aliases h, wtq head)
    float* lpart = (float*)(ws + 16777216);      //  2 x 65536 f32 (inside wtq region)

    rmsnorm_kernel<<<4096, 256, 0, stream>>>(x, rms_w, h);
    wtrans_kernel<<<dim3(32, 32, 4), 256, 0, stream>>>(Wq, Wk, Wv, Wo, wtq, wto);
    gemm_qkv_kernel<<<dim3(48, 32), 256, 0, stream>>>(h, wtq, cosp, sinp, qk, vT);
    attn_kernel<<<512, 256, 0, stream>>>(qk, qk + 8388608, vT, Opart, lpart);
    combine_kernel<<<512, 256, 0, stream>>>(Opart, lpart, attn);
    gemm_out_kernel<<<dim3(16, 32), 256, 0, stream>>>(attn, wto, x, out);
}

// Round 7
// 407.512 us; speedup vs baseline: 1.2487x; 1.2487x over previous
//
#include <hip/hip_runtime.h>

#define HID   2048
#define S_LEN 2048
#define NHEAD 16
#define HD    128
#define NKV   2048   // NH*HD

typedef __attribute__((ext_vector_type(8))) short   short8;
typedef __attribute__((ext_vector_type(4))) float   floatx4;

__device__ __forceinline__ unsigned short f2bf(float f) {
    union { float f; unsigned u; } v; v.f = f;
    unsigned r = v.u + 0x7fffu + ((v.u >> 16) & 1u);
    return (unsigned short)(r >> 16);
}
__device__ __forceinline__ float bf2f(unsigned short h) {
    union { unsigned u; float f; } v; v.u = ((unsigned)h) << 16; return v.f;
}

// async global->LDS, 16B per lane; LDS dest must be wave-uniform base + lane*16
__device__ __forceinline__ void async16(void* lds, const void* g) {
    __builtin_amdgcn_global_load_lds(
        (const __attribute__((address_space(1))) unsigned int*)g,
        (__attribute__((address_space(3))) unsigned int*)lds, 16, 0, 0);
}

// ---------------- RMSNorm: x(f32) -> h(bf16) ----------------
__global__ __launch_bounds__(256) void rmsnorm_kernel(const float* __restrict__ x,
        const float* __restrict__ w, unsigned short* __restrict__ h) {
    const int row = blockIdx.x;
    const int t = threadIdx.x;
    const float* xr = x + (size_t)row * HID;
    float4 v0 = *(const float4*)(xr + t * 4);
    float4 v1 = *(const float4*)(xr + 1024 + t * 4);
    float ss = v0.x*v0.x + v0.y*v0.y + v0.z*v0.z + v0.w*v0.w
             + v1.x*v1.x + v1.y*v1.y + v1.z*v1.z + v1.w*v1.w;
    #pragma unroll
    for (int off = 1; off < 64; off <<= 1) ss += __shfl_xor(ss, off, 64);
    __shared__ float red[4];
    if ((t & 63) == 0) red[t >> 6] = ss;
    __syncthreads();
    float tot = red[0] + red[1] + red[2] + red[3];
    float inv = rsqrtf(tot * (1.0f / HID) + 1e-5f);
    float4 w0 = *(const float4*)(w + t * 4);
    float4 w1 = *(const float4*)(w + 1024 + t * 4);
    ushort4 o0, o1;
    o0.x = f2bf(v0.x * inv * w0.x); o0.y = f2bf(v0.y * inv * w0.y);
    o0.z = f2bf(v0.z * inv * w0.z); o0.w = f2bf(v0.w * inv * w0.w);
    o1.x = f2bf(v1.x * inv * w1.x); o1.y = f2bf(v1.y * inv * w1.y);
    o1.z = f2bf(v1.z * inv * w1.z); o1.w = f2bf(v1.w * inv * w1.w);
    *(ushort4*)(h + (size_t)row * HID + t * 4) = o0;
    *(ushort4*)(h + (size_t)row * HID + 1024 + t * 4) = o1;
}

// ------------- weight cast+transpose: W[k][n](f32) -> Wt[n][k](bf16) -------------
__global__ __launch_bounds__(256) void wtrans_kernel(const float* __restrict__ Wq,
        const float* __restrict__ Wk, const float* __restrict__ Wv,
        const float* __restrict__ Wo,
        unsigned short* __restrict__ wt_qkv, unsigned short* __restrict__ wt_o) {
    __shared__ float tile[64][65];
    const int sel = blockIdx.z;
    const float* W = (sel == 0) ? Wq : (sel == 1) ? Wk : (sel == 2) ? Wv : Wo;
    const int n0 = blockIdx.x * 64, k0 = blockIdx.y * 64;
    const int t = threadIdx.x;
    const int col = t & 63, r4 = t >> 6;
    #pragma unroll
    for (int i = 0; i < 16; ++i) {
        int rr = r4 + i * 4;
        tile[rr][col] = W[(size_t)(k0 + rr) * NKV + n0 + col];
    }
    __syncthreads();
    #pragma unroll
    for (int i = 0; i < 16; ++i) {
        int rr = r4 + i * 4;
        unsigned short v = f2bf(tile[col][rr]);
        if (sel < 3) wt_qkv[((size_t)(sel * 2048 + n0 + rr)) * HID + k0 + col] = v;
        else         wt_o  [((size_t)(n0 + rr)) * HID + k0 + col] = v;
    }
}

// ------------- GEMM mainloop: C(128x128) = A[M][K](bf16) * Bt[N][K](bf16)^T -------------
__device__ __forceinline__ void gemm_body(const unsigned short* __restrict__ A,
        const unsigned short* __restrict__ Bt, int K, int rowBase, int colBase,
        unsigned short* As, unsigned short* Bs, floatx4 acc[4][4]) {
    const int t = threadIdx.x;
    const int lane = t & 63, w = t >> 6;
    const int wm = (w >> 1) * 64, wsel = w & 1;
    const int lr = lane & 15, quad = lane >> 4;
    #pragma unroll
    for (int mi = 0; mi < 4; ++mi)
        #pragma unroll
        for (int ni = 0; ni < 4; ++ni) {
            acc[mi][ni][0] = 0.f; acc[mi][ni][1] = 0.f;
            acc[mi][ni][2] = 0.f; acc[mi][ni][3] = 0.f;
        }
    for (int k0 = 0; k0 < K; k0 += 64) {
        __syncthreads();
        #pragma unroll
        for (int c = 0; c < 4; ++c) {
            int e = (c * 256 + t) * 8;          // LDS element offset
            int r = e >> 6;                     // tile row
            int chunk = ((e >> 3) & 7) ^ (r & 7);  // logical 8-el chunk
            async16(As + e, A  + (size_t)(rowBase + r) * K + k0 + chunk * 8);
            async16(Bs + e, Bt + (size_t)(colBase + r) * K + k0 + chunk * 8);
        }
        __syncthreads();
        #pragma unroll
        for (int ks = 0; ks < 2; ++ks) {
            short8 af[4], bfr[4];
            int cp = (ks * 4 + quad) ^ (lr & 7);
            #pragma unroll
            for (int i = 0; i < 4; ++i)
                af[i] = *(const short8*)(As + (wm + i * 16 + lr) * 64 + cp * 8);
            #pragma unroll
            for (int i = 0; i < 4; ++i)
                bfr[i] = *(const short8*)(Bs + (i * 32 + wsel * 16 + lr) * 64 + cp * 8);
            #pragma unroll
            for (int mi = 0; mi < 4; ++mi)
                #pragma unroll
                for (int ni = 0; ni < 4; ++ni)
                    acc[mi][ni] = __builtin_amdgcn_mfma_f32_16x16x32_bf16(
                        af[mi], bfr[ni], acc[mi][ni], 0, 0, 0);
        }
    }
}

// ------------- QKV GEMM: h @ Wqkv, fused RoPE; scatters q,k (b,h,s,d) and v^T (b,h,d,s) -------------
__global__ __launch_bounds__(256) void gemm_qkv_kernel(const unsigned short* __restrict__ h,
        const unsigned short* __restrict__ wt, const float* __restrict__ cosp,
        const float* __restrict__ sinp, unsigned short* __restrict__ qk,
        unsigned short* __restrict__ vT) {
    __shared__ __align__(16) unsigned short As[128 * 64];
    __shared__ __align__(16) unsigned short Bs[128 * 64];
    floatx4 acc[4][4];
    const int rowBase = blockIdx.y * 128, colBase = blockIdx.x * 128;
    gemm_body(h, wt, HID, rowBase, colBase, As, Bs, acc);
    const int t = threadIdx.x, lane = t & 63, w = t >> 6;
    const int wm = (w >> 1) * 64, wsel = w & 1;
    const int lr = lane & 15, quad = lane >> 4;
    const int sel = colBase >> 11;
    const int hh = (colBase >> 7) & 15;
    #pragma unroll
    for (int mi = 0; mi < 4; ++mi) {
        int row0 = rowBase + wm + mi * 16 + quad * 4;
        int b = row0 >> 11, s0 = row0 & 2047;
        if (sel < 2) {
            unsigned short* base = qk + (size_t)sel * 8388608
                                 + ((size_t)(b * NHEAD + hh) * S_LEN) * HD;
            #pragma unroll
            for (int ni = 0; ni < 2; ++ni) {
                int d = ni * 32 + wsel * 16 + lr;      // [0,64)
                #pragma unroll
                for (int r = 0; r < 4; ++r) {
                    int s = s0 + r;
                    float c  = cosp[s * 64 + d];
                    float sn = sinp[s * 64 + d];
                    float v1 = acc[mi][ni][r], v2 = acc[mi][ni + 2][r];
                    base[(size_t)s * HD + d]      = f2bf(v1 * c - v2 * sn);
                    base[(size_t)s * HD + d + 64] = f2bf(v2 * c + v1 * sn);
                }
            }
        } else {
            #pragma unroll
            for (int ni = 0; ni < 4; ++ni) {
                int d = ni * 32 + wsel * 16 + lr;
                ushort4 pk;
                pk.x = f2bf(acc[mi][ni][0]); pk.y = f2bf(acc[mi][ni][1]);
                pk.z = f2bf(acc[mi][ni][2]); pk.w = f2bf(acc[mi][ni][3]);
                *(ushort4*)(vT + ((size_t)(b * NHEAD + hh) * HD + d) * S_LEN + s0) = pk;
            }
        }
    }
}

// ------------- causal flash attention: 64-row q-tiles, 32-key tiles, 4 blocks/CU -------------
// 1024 uniform blocks (33 iters each): q-tile pair (31-j, j) per bh, 2-role key split.
// K/V double-buffered via global_load_lds (36 KB LDS). Fixed softmax max=0; bf16
// partials + f32 row-sums combined by combine_kernel.
__global__ __launch_bounds__(256, 4) void attn_kernel(const unsigned short* __restrict__ q,
        const unsigned short* __restrict__ k, const unsigned short* __restrict__ vT,
        unsigned short* __restrict__ Opart, float* __restrict__ lpart) {
    __shared__ __align__(16) unsigned short Kd[2][32 * 128];  // [key][d], 16-chunk xor swizzle
    __shared__ __align__(16) unsigned short Vd[2][128 * 32];  // [d][key], 4-chunk xor swizzle
    __shared__ __align__(16) unsigned short Ps[4][16 * 32];   // per-wave P, 4-chunk xor swizzle

    const int id = blockIdx.x;            // 0..1023
    const int bh   = id >> 5;             // 0..31
    const int j    = (id >> 1) & 15;      // 0..15
    const int role = id & 1;              // 0=A (first key-halves), 1=B (second)

    const int segqt[2] = {31 - j, j};     // 64-row q-tiles

    const unsigned short* qb = q  + (size_t)bh * S_LEN * HD;
    const unsigned short* kb = k  + (size_t)bh * S_LEN * HD;
    const unsigned short* vb = vT + (size_t)bh * HD * S_LEN;
    const int t = threadIdx.x, lane = t & 63, w = t >> 6;
    const int lr = lane & 15, quad = lane >> 4;
    const float SC = 0.1275174855f;  // (1/sqrt(128)) * log2(e)

    short8 qf[4];
    floatx4 o[8];
    float rs[4] = {0.f, 0.f, 0.f, 0.f};
    #pragma unroll
    for (int i = 0; i < 8; ++i) { o[i][0]=0.f; o[i][1]=0.f; o[i][2]=0.f; o[i][3]=0.f; }

    auto loadq = [&](int qt) {
        int qrow = qt * 64 + w * 16 + lr;
        #pragma unroll
        for (int ks = 0; ks < 4; ++ks) {
            short8 raw = *(const short8*)(qb + (size_t)qrow * HD + ks * 32 + quad * 8);
            #pragma unroll
            for (int jj = 0; jj < 8; ++jj)
                qf[ks][jj] = (short)f2bf(bf2f((unsigned short)raw[jj]) * SC);
        }
    };

    // stage 32-key tile kt2 into buffer buf (K: 8 KB, V: 8 KB)
    auto stage = [&](int kt2, int buf) {
        unsigned short* Kb = &Kd[buf][0];
        unsigned short* Vb = &Vd[buf][0];
        #pragma unroll
        for (int c = 0; c < 2; ++c) {
            int e = (c * 256 + t) * 8;
            int kr = e >> 7;                        // key row 0..31
            int kch = ((e >> 3) & 15) ^ (kr & 15);
            async16(Kb + e, kb + (size_t)(kt2 * 32 + kr) * HD + kch * 8);
            int vr = e >> 5;                        // d row 0..127
            int vch = ((e >> 3) & 3) ^ (vr & 3);
            async16(Vb + e, vb + (size_t)vr * S_LEN + kt2 * 32 + vch * 8);
        }
    };

    auto tilework = [&](int qt, int kt, int buf, bool maskf) {
        const unsigned short* Ksb = &Kd[buf][0];
        const unsigned short* Vsb = &Vd[buf][0];
        floatx4 sc[2];
        sc[0][0]=0.f; sc[0][1]=0.f; sc[0][2]=0.f; sc[0][3]=0.f;
        sc[1][0]=0.f; sc[1][1]=0.f; sc[1][2]=0.f; sc[1][3]=0.f;
        #pragma unroll
        for (int ks = 0; ks < 4; ++ks)
            #pragma unroll
            for (int ni = 0; ni < 2; ++ni) {
                int row = ni * 16 + lr;
                int cp = (ks * 4 + quad) ^ (row & 15);
                short8 kf = *(const short8*)(Ksb + row * 128 + cp * 8);
                sc[ni] = __builtin_amdgcn_mfma_f32_16x16x32_bf16(qf[ks], kf, sc[ni], 0, 0, 0);
            }
        const int row_out = qt * 64 + w * 16 + quad * 4;
        #pragma unroll
        for (int ni = 0; ni < 2; ++ni) {
            int key = kt * 32 + ni * 16 + lr;
            #pragma unroll
            for (int r = 0; r < 4; ++r) {
                float p = exp2f(sc[ni][r]);
                if (maskf && key > row_out + r) p = 0.f;
                rs[r] += p;
                int prow = quad * 4 + r;
                int chunk = (ni * 2 + (lr >> 3)) ^ (prow & 3);
                Ps[w][prow * 32 + chunk * 8 + (lr & 7)] =
                    (unsigned short)(__float_as_uint(p) >> 16);
            }
        }
        // P @ V: one A-frag (16 rows x 32 keys), 8 V-frags
        short8 pa = *(const short8*)(&Ps[w][lr * 32 + (quad ^ (lr & 3)) * 8]);
        #pragma unroll
        for (int nt = 0; nt < 8; ++nt) {
            int vrow = nt * 16 + lr;
            int vcp = quad ^ (vrow & 3);
            short8 vf = *(const short8*)(Vsb + vrow * 32 + vcp * 8);
            o[nt] = __builtin_amdgcn_mfma_f32_16x16x32_bf16(pa, vf, o[nt], 0, 0, 0);
        }
    };

    // flush partials for q-tile qt, reset accumulators
    auto flushseg = [&](int qt) {
        unsigned short* ob = Opart + (size_t)role * 8388608
                           + ((size_t)(bh * 32 + qt) * 64) * 128;
        float* lb = lpart + role * 65536 + (bh * 32 + qt) * 64;
        int qrow0 = w * 16 + quad * 4;
        #pragma unroll
        for (int r = 0; r < 4; ++r) {
            float s2 = rs[r];
            #pragma unroll
            for (int off = 1; off < 16; off <<= 1) s2 += __shfl_xor(s2, off, 64);
            if (lr == 0) lb[qrow0 + r] = s2;
            rs[r] = 0.f;
        }
        #pragma unroll
        for (int nt = 0; nt < 8; ++nt) {
            int col = nt * 16 + lr;
            #pragma unroll
            for (int r = 0; r < 4; ++r)
                ob[(size_t)(qrow0 + r) * 128 + col] = f2bf(o[nt][r]);
            o[nt][0]=0.f; o[nt][1]=0.f; o[nt][2]=0.f; o[nt][3]=0.f;
        }
    };

    // segment s: q-tile qt = segqt[s]; its k-tiles n = 2qt+2; this role takes
    // half: k0 = role*(qt+1), len = qt+1.
    {
        int qt0 = segqt[0];
        stage(role * (qt0 + 1), 0);
    }
    int g = 0;
    for (int s = 0; s < 2; ++s) {
        const int qt = segqt[s];
        const int k0 = role * (qt + 1), len = qt + 1;
        loadq(qt);
        for (int i = 0; i < len; ++i, ++g) {
            __syncthreads();   // drains stage issued last iter
            // prefetch next tile (possibly next segment's first)
            int ns = s, nidx = i + 1;
            if (nidx == len) { ns = s + 1; nidx = 0; }
            if (ns < 2) {
                int nqt = segqt[ns];
                stage(role * (nqt + 1) + nidx, (g + 1) & 1);
            }
            int kt = k0 + i;
            tilework(qt, kt, g & 1, kt >= 2 * qt);
        }
        flushseg(qt);
    }
}

// ------------- combine partials: attn = (OA+OB) / (lA+lB) -------------
// grid 1024: one block per (bh, 64-row q-tile)
__global__ __launch_bounds__(256) void combine_kernel(const unsigned short* __restrict__ Opart,
        const float* __restrict__ lpart, unsigned short* __restrict__ attn) {
    const int T = blockIdx.x;        // bh*32 + qt
    const int bh = T >> 5, qt = T & 31;
    const int b = bh >> 4, hh = bh & 15;
    const int t = threadIdx.x;
    const int qrow = t >> 2, quarter = t & 3;   // 64 rows x 4 col-quarters of 32
    float rl = 1.0f / (lpart[T * 64 + qrow] + lpart[65536 + T * 64 + qrow]);
    const unsigned short* pa = Opart + ((size_t)T * 64 + qrow) * 128 + quarter * 32;
    const unsigned short* pb = pa + 8388608;
    unsigned short* po = attn + ((size_t)(b * S_LEN + qt * 64 + qrow)) * NKV
                       + hh * HD + quarter * 32;
    #pragma unroll
    for (int c = 0; c < 4; ++c) {
        short8 a8 = *(const short8*)(pa + c * 8);
        short8 b8 = *(const short8*)(pb + c * 8);
        short8 o8;
        #pragma unroll
        for (int jj = 0; jj < 8; ++jj)
            o8[jj] = (short)f2bf((bf2f((unsigned short)a8[jj]) + bf2f((unsigned short)b8[jj])) * rl);
        *(short8*)(po + c * 8) = o8;
    }
}

// ------------- output GEMM + residual -------------
__global__ __launch_bounds__(256) void gemm_out_kernel(const unsigned short* __restrict__ attn,
        const unsigned short* __restrict__ wto, const float* __restrict__ x,
        float* __restrict__ out) {
    __shared__ __align__(16) unsigned short As[128 * 64];
    __shared__ __align__(16) unsigned short Bs[128 * 64];
    floatx4 acc[4][4];
    const int rowBase = blockIdx.y * 128, colBase = blockIdx.x * 128;
    gemm_body(attn, wto, NKV, rowBase, colBase, As, Bs, acc);
    const int t = threadIdx.x, lane = t & 63, w = t >> 6;
    const int wm = (w >> 1) * 64, wsel = w & 1;
    const int lr = lane & 15, quad = lane >> 4;
    #pragma unroll
    for (int mi = 0; mi < 4; ++mi) {
        int row0 = rowBase + wm + mi * 16 + quad * 4;
        #pragma unroll
        for (int ni = 0; ni < 4; ++ni) {
            int col = colBase + ni * 32 + wsel * 16 + lr;
            #pragma unroll
            for (int r = 0; r < 4; ++r) {
                size_t off = (size_t)(row0 + r) * HID + col;
                out[off] = acc[mi][ni][r] + x[off];
            }
        }
    }
}

extern "C" void kernel_launch(void* const* d_in, const int* in_sizes, int n_in,
                              void* d_out, int out_size, void* d_ws, size_t ws_size,
                              hipStream_t stream) {
    const float* x     = (const float*)d_in[0];
    const float* rms_w = (const float*)d_in[1];
    const float* Wq    = (const float*)d_in[2];
    const float* Wk    = (const float*)d_in[3];
    const float* Wv    = (const float*)d_in[4];
    const float* Wo    = (const float*)d_in[5];
    const float* cosp  = (const float*)d_in[6];
    const float* sinp  = (const float*)d_in[7];
    float* out = (float*)d_out;

    unsigned short* ws   = (unsigned short*)d_ws;
    unsigned short* h    = ws;                   //  8388608 el (dead after qkv -> Opart role A)
    unsigned short* wtq  = ws + 8388608;         // 12582912 el (dead after qkv -> Opart role B + lpart)
    unsigned short* wto  = ws + 20971520;        //  4194304 el (Wo^T)
    unsigned short* qk   = ws + 25165824;        //  q then k, 2x8388608
    unsigned short* vT   = ws + 41943040;        //  8388608 el (b,h,d,s)
    unsigned short* attn = ws + 50331648;        //  8388608 el (b*s, h*d)
    unsigned short* Opart = ws;                  //  2 x 8388608 el (aliases h, wtq head)
    float* lpart = (float*)(ws + 16777216);      //  2 x 65536 f32 (inside wtq region)

    rmsnorm_kernel<<<4096, 256, 0, stream>>>(x, rms_w, h);
    wtrans_kernel<<<dim3(32, 32, 4), 256, 0, stream>>>(Wq, Wk, Wv, Wo, wtq, wto);
    gemm_qkv_kernel<<<dim3(48, 32), 256, 0, stream>>>(h, wtq, cosp, sinp, qk, vT);
    attn_kernel<<<1024, 256, 0, stream>>>(qk, qk + 8388608, vT, Opart, lpart);
    combine_kernel<<<1024, 256, 0, stream>>>(Opart, lpart, attn);
    gemm_out_kernel<<<dim3(16, 32), 256, 0, stream>>>(attn, wto, x, out);
}